// Round 2
// baseline (169.639 us; speedup 1.0000x reference)
//
#include <hip/hip_runtime.h>

// B=4, S=2048, D=1024, N=65536, K=16  -> T = B*S = 8192 tokens
#define TOKENS 8192
#define DIM    1024
#define TOPK   16
#define NTHREADS 256

// -------- Kernel A: sense --------
// One block per token. Thread layout: k = tid>>4 (16 threads per k), j = tid&15.
// Each thread dots 64 elements of x against emb[idx[k]] (16 float4 @ stride 16
// float4), then a 4-step shfl_xor reduce within the 16-lane group. No barrier
// after the loads, no cross-wave reduction.
__global__ __launch_bounds__(NTHREADS) void sense_kernel(
    const float* __restrict__ x,      // [T, D]
    const float* __restrict__ emb,    // [N, D]
    const float* __restrict__ gate,   // [T, K]
    const int*   __restrict__ idx,    // [T, K]
    float*       __restrict__ gated)  // [T, K]  (workspace)
{
    const int t   = blockIdx.x;
    const int tid = threadIdx.x;

    __shared__ float4 sx[DIM / 4];   // 4 KB: x row staged once, broadcast reads
    __shared__ int    sidx[TOPK];

    if (tid < TOPK) sidx[tid] = idx[(size_t)t * TOPK + tid];
    sx[tid] = reinterpret_cast<const float4*>(x + (size_t)t * DIM)[tid];
    __syncthreads();

    const int k = tid >> 4;
    const int j = tid & 15;
    const float4* row = reinterpret_cast<const float4*>(
        emb + (size_t)sidx[k] * DIM);

    float acc = 0.f;
    #pragma unroll
    for (int i = 0; i < 16; ++i) {
        const float4 e  = row[j + 16 * i];
        const float4 xv = sx[j + 16 * i];   // same addr across the 4 groups -> broadcast
        acc += e.x * xv.x + e.y * xv.y + e.z * xv.z + e.w * xv.w;
    }

    // reduce across the 16 lanes of this k-group (stays inside the wave)
    acc += __shfl_xor(acc, 1, 64);
    acc += __shfl_xor(acc, 2, 64);
    acc += __shfl_xor(acc, 4, 64);
    acc += __shfl_xor(acc, 8, 64);

    if (j == 0)
        gated[(size_t)t * TOPK + k] = acc * gate[(size_t)t * TOPK + k];
}

// -------- Kernel B: emit --------
// One block per token, one float4 of the output row per thread. Pure
// gather-FMA-store, no reductions, single barrier for the tiny LDS stage.
__global__ __launch_bounds__(NTHREADS) void emit_kernel(
    const float* __restrict__ w,      // [N, D]
    const float* __restrict__ gated,  // [T, K]
    const int*   __restrict__ idx,    // [T, K]
    float*       __restrict__ out)    // [T, D]
{
    const int t   = blockIdx.x;
    const int tid = threadIdx.x;

    __shared__ int   sidx[TOPK];
    __shared__ float sg[TOPK];

    if (tid < TOPK) {
        sidx[tid] = idx[(size_t)t * TOPK + tid];
        sg[tid]   = gated[(size_t)t * TOPK + tid];
    }
    __syncthreads();

    float ax = 0.f, ay = 0.f, az = 0.f, aw = 0.f;
    #pragma unroll
    for (int k = 0; k < TOPK; ++k) {
        const float g = sg[k];
        const float4 wv = reinterpret_cast<const float4*>(
            w + (size_t)sidx[k] * DIM)[tid];
        ax += g * wv.x; ay += g * wv.y; az += g * wv.z; aw += g * wv.w;
    }
    reinterpret_cast<float4*>(out + (size_t)t * DIM)[tid] =
        make_float4(ax, ay, az, aw);
}

extern "C" void kernel_launch(void* const* d_in, const int* in_sizes, int n_in,
                              void* d_out, int out_size, void* d_ws, size_t ws_size,
                              hipStream_t stream) {
    const float* x    = (const float*)d_in[0];  // [B,S,D]
    const float* emb  = (const float*)d_in[1];  // [N,D]
    const float* w    = (const float*)d_in[2];  // [N,D]
    const float* gate = (const float*)d_in[3];  // [B,S,K]
    const int*   idx  = (const int*)d_in[4];    // [B,S,K]
    float*       out  = (float*)d_out;          // [B,S,D]
    float*       gated = (float*)d_ws;          // [T,K] = 512 KB scratch

    sense_kernel<<<TOKENS, NTHREADS, 0, stream>>>(x, emb, gate, idx, gated);
    emit_kernel <<<TOKENS, NTHREADS, 0, stream>>>(w, gated, idx, out);
}

// Round 3
// 168.951 us; speedup vs baseline: 1.0041x; 1.0041x over previous
//
#include <hip/hip_runtime.h>

// B=4, S=2048, D=1024, N=65536, K=16  -> T = B*S = 8192 tokens
#define TOKENS 8192
#define DIM    1024
#define TOPK   16
#define NT     256

// -------- Kernel A: sense --------
// One block per token. k = tid>>4 (16 threads per k), j = tid&15.
// No LDS, no barriers. Each thread: 16 emb float4 + 16 x float4, issued in
// two explicit depth-16 batches (8 e + 8 x in flight) to maximize MLP.
__global__ __launch_bounds__(NT) void sense_kernel(
    const float* __restrict__ x,      // [T, D]
    const float* __restrict__ emb,    // [N, D]
    const float* __restrict__ gate,   // [T, K]
    const int*   __restrict__ idx,    // [T, K]
    float*       __restrict__ gated)  // [T, K]
{
    const int t   = blockIdx.x;
    const int tid = threadIdx.x;
    const int k   = tid >> 4;
    const int j   = tid & 15;

    const int row = idx[t * TOPK + k];            // 16-lane broadcast load

    const float4* e  = reinterpret_cast<const float4*>(emb + (size_t)row * DIM) + j;
    const float4* xv = reinterpret_cast<const float4*>(x   + (size_t)t   * DIM) + j;

    // ---- batch 1: 8 e-loads + 8 x-loads in flight ----
    float4 e0 = e[0*16], e1 = e[1*16], e2 = e[2*16], e3 = e[3*16];
    float4 e4 = e[4*16], e5 = e[5*16], e6 = e[6*16], e7 = e[7*16];
    float4 x0 = xv[0*16], x1 = xv[1*16], x2 = xv[2*16], x3 = xv[3*16];
    float4 x4 = xv[4*16], x5 = xv[5*16], x6 = xv[6*16], x7 = xv[7*16];

    float acc;
    acc  = e0.x*x0.x + e0.y*x0.y + e0.z*x0.z + e0.w*x0.w;
    acc += e1.x*x1.x + e1.y*x1.y + e1.z*x1.z + e1.w*x1.w;
    acc += e2.x*x2.x + e2.y*x2.y + e2.z*x2.z + e2.w*x2.w;
    acc += e3.x*x3.x + e3.y*x3.y + e3.z*x3.z + e3.w*x3.w;
    acc += e4.x*x4.x + e4.y*x4.y + e4.z*x4.z + e4.w*x4.w;
    acc += e5.x*x5.x + e5.y*x5.y + e5.z*x5.z + e5.w*x5.w;
    acc += e6.x*x6.x + e6.y*x6.y + e6.z*x6.z + e6.w*x6.w;
    acc += e7.x*x7.x + e7.y*x7.y + e7.z*x7.z + e7.w*x7.w;

    // ---- batch 2 ----
    float4 f0 = e[ 8*16], f1 = e[ 9*16], f2 = e[10*16], f3 = e[11*16];
    float4 f4 = e[12*16], f5 = e[13*16], f6 = e[14*16], f7 = e[15*16];
    float4 y0 = xv[ 8*16], y1 = xv[ 9*16], y2 = xv[10*16], y3 = xv[11*16];
    float4 y4 = xv[12*16], y5 = xv[13*16], y6 = xv[14*16], y7 = xv[15*16];

    acc += f0.x*y0.x + f0.y*y0.y + f0.z*y0.z + f0.w*y0.w;
    acc += f1.x*y1.x + f1.y*y1.y + f1.z*y1.z + f1.w*y1.w;
    acc += f2.x*y2.x + f2.y*y2.y + f2.z*y2.z + f2.w*y2.w;
    acc += f3.x*y3.x + f3.y*y3.y + f3.z*y3.z + f3.w*y3.w;
    acc += f4.x*y4.x + f4.y*y4.y + f4.z*y4.z + f4.w*y4.w;
    acc += f5.x*y5.x + f5.y*y5.y + f5.z*y5.z + f5.w*y5.w;
    acc += f6.x*y6.x + f6.y*y6.y + f6.z*y6.z + f6.w*y6.w;
    acc += f7.x*y7.x + f7.y*y7.y + f7.z*y7.z + f7.w*y7.w;

    // reduce across the 16 lanes of this k-group (intra-wave)
    acc += __shfl_xor(acc, 1, 64);
    acc += __shfl_xor(acc, 2, 64);
    acc += __shfl_xor(acc, 4, 64);
    acc += __shfl_xor(acc, 8, 64);

    if (j == 0)
        gated[t * TOPK + k] = acc * gate[t * TOPK + k];
}

// -------- Kernel B: emit --------
// One block per token, one float4 of the output row per thread. No LDS, no
// barriers: every thread loads the (block-uniform) idx/gated rows itself,
// then 16 gathers in two explicit depth-8 batches.
__global__ __launch_bounds__(NT) void emit_kernel(
    const float* __restrict__ w,      // [N, D]
    const float* __restrict__ gated,  // [T, K]
    const int*   __restrict__ idx,    // [T, K]
    float*       __restrict__ out)    // [T, D]
{
    const int t   = blockIdx.x;
    const int tid = threadIdx.x;

    const int4*   iv = reinterpret_cast<const int4*>(idx   + t * TOPK);
    const float4* gv = reinterpret_cast<const float4*>(gated + t * TOPK);
    const int4   i0 = iv[0], i1 = iv[1], i2 = iv[2], i3 = iv[3];
    const float4 g0 = gv[0], g1 = gv[1], g2 = gv[2], g3 = gv[3];

    const float4* wb = reinterpret_cast<const float4*>(w);  // row r: wb[r*256 + tid]

    // ---- batch 1: 8 gathers in flight ----
    float4 r0 = wb[(size_t)i0.x * (DIM/4) + tid];
    float4 r1 = wb[(size_t)i0.y * (DIM/4) + tid];
    float4 r2 = wb[(size_t)i0.z * (DIM/4) + tid];
    float4 r3 = wb[(size_t)i0.w * (DIM/4) + tid];
    float4 r4 = wb[(size_t)i1.x * (DIM/4) + tid];
    float4 r5 = wb[(size_t)i1.y * (DIM/4) + tid];
    float4 r6 = wb[(size_t)i1.z * (DIM/4) + tid];
    float4 r7 = wb[(size_t)i1.w * (DIM/4) + tid];

    float ax, ay, az, aw;
    ax  = g0.x*r0.x; ay  = g0.x*r0.y; az  = g0.x*r0.z; aw  = g0.x*r0.w;
    ax += g0.y*r1.x; ay += g0.y*r1.y; az += g0.y*r1.z; aw += g0.y*r1.w;
    ax += g0.z*r2.x; ay += g0.z*r2.y; az += g0.z*r2.z; aw += g0.z*r2.w;
    ax += g0.w*r3.x; ay += g0.w*r3.y; az += g0.w*r3.z; aw += g0.w*r3.w;
    ax += g1.x*r4.x; ay += g1.x*r4.y; az += g1.x*r4.z; aw += g1.x*r4.w;
    ax += g1.y*r5.x; ay += g1.y*r5.y; az += g1.y*r5.z; aw += g1.y*r5.w;
    ax += g1.z*r6.x; ay += g1.z*r6.y; az += g1.z*r6.z; aw += g1.z*r6.w;
    ax += g1.w*r7.x; ay += g1.w*r7.y; az += g1.w*r7.z; aw += g1.w*r7.w;

    // ---- batch 2 ----
    float4 s0 = wb[(size_t)i2.x * (DIM/4) + tid];
    float4 s1 = wb[(size_t)i2.y * (DIM/4) + tid];
    float4 s2 = wb[(size_t)i2.z * (DIM/4) + tid];
    float4 s3 = wb[(size_t)i2.w * (DIM/4) + tid];
    float4 s4 = wb[(size_t)i3.x * (DIM/4) + tid];
    float4 s5 = wb[(size_t)i3.y * (DIM/4) + tid];
    float4 s6 = wb[(size_t)i3.z * (DIM/4) + tid];
    float4 s7 = wb[(size_t)i3.w * (DIM/4) + tid];

    ax += g2.x*s0.x; ay += g2.x*s0.y; az += g2.x*s0.z; aw += g2.x*s0.w;
    ax += g2.y*s1.x; ay += g2.y*s1.y; az += g2.y*s1.z; aw += g2.y*s1.w;
    ax += g2.z*s2.x; ay += g2.z*s2.y; az += g2.z*s2.z; aw += g2.z*s2.w;
    ax += g2.w*s3.x; ay += g2.w*s3.y; az += g2.w*s3.z; aw += g2.w*s3.w;
    ax += g3.x*s4.x; ay += g3.x*s4.y; az += g3.x*s4.z; aw += g3.x*s4.w;
    ax += g3.y*s5.x; ay += g3.y*s5.y; az += g3.y*s5.z; aw += g3.y*s5.w;
    ax += g3.z*s6.x; ay += g3.z*s6.y; az += g3.z*s6.z; aw += g3.z*s6.w;
    ax += g3.w*s7.x; ay += g3.w*s7.y; az += g3.w*s7.z; aw += g3.w*s7.w;

    reinterpret_cast<float4*>(out + (size_t)t * DIM)[tid] =
        make_float4(ax, ay, az, aw);
}

extern "C" void kernel_launch(void* const* d_in, const int* in_sizes, int n_in,
                              void* d_out, int out_size, void* d_ws, size_t ws_size,
                              hipStream_t stream) {
    const float* x    = (const float*)d_in[0];  // [B,S,D]
    const float* emb  = (const float*)d_in[1];  // [N,D]
    const float* w    = (const float*)d_in[2];  // [N,D]
    const float* gate = (const float*)d_in[3];  // [B,S,K]
    const int*   idx  = (const int*)d_in[4];    // [B,S,K]
    float*       out  = (float*)d_out;          // [B,S,D]
    float*       gated = (float*)d_ws;          // [T,K] = 512 KB scratch

    sense_kernel<<<TOKENS, NT, 0, stream>>>(x, emb, gate, idx, gated);
    emit_kernel <<<TOKENS, NT, 0, stream>>>(w, gated, idx, out);
}

// Round 4
// 163.009 us; speedup vs baseline: 1.0407x; 1.0365x over previous
//
#include <hip/hip_runtime.h>

// B=4, S=2048, D=1024, N=65536, K=16  -> T = B*S = 8192 tokens
// Fused sense+emit: one block per token, one kernel launch total.
//   Phase 1 (sense): k = tid>>4, j = tid&15 -> 16 lanes per k.
//     Each lane dots 64 elems of x[t] with emb[idx[k]] (16 float4 @ stride 16),
//     4-step intra-wave shfl_xor reduce, lane j==0 writes gated[k] to LDS.
//   Phase 2 (emit): one barrier, then each thread owns one float4 of out[t],
//     16 coalesced w-row gathers, FMA with LDS-broadcast gains, one store.
#define TOKENS 8192
#define DIM    1024
#define TOPK   16
#define NT     256

__global__ __launch_bounds__(NT) void kc_fused_kernel(
    const float* __restrict__ x,      // [T, D]
    const float* __restrict__ emb,    // [N, D]
    const float* __restrict__ w,      // [N, D]
    const float* __restrict__ gate,   // [T, K]
    const int*   __restrict__ idx,    // [T, K]
    float*       __restrict__ out)    // [T, D]
{
    const int t   = blockIdx.x;
    const int tid = threadIdx.x;
    const int k   = tid >> 4;
    const int j   = tid & 15;

    __shared__ float sg[TOPK];

    // ---- Phase 1: sense ----
    const int row = idx[t * TOPK + k];                 // 16-lane broadcast load

    const float4* e  = reinterpret_cast<const float4*>(emb) + (size_t)row * (DIM / 4) + j;
    const float4* xv = reinterpret_cast<const float4*>(x)   + (size_t)t   * (DIM / 4) + j;

    float acc = 0.f;
    #pragma unroll
    for (int i = 0; i < 16; ++i) {
        const float4 ev = e[16 * i];
        const float4 xw = xv[16 * i];
        acc += ev.x * xw.x + ev.y * xw.y + ev.z * xw.z + ev.w * xw.w;
    }

    // reduce across the 16 lanes of this k-group (intra-wave)
    acc += __shfl_xor(acc, 1, 64);
    acc += __shfl_xor(acc, 2, 64);
    acc += __shfl_xor(acc, 4, 64);
    acc += __shfl_xor(acc, 8, 64);

    if (j == 0)
        sg[k] = acc * gate[t * TOPK + k];
    __syncthreads();

    // ---- Phase 2: emit ----
    const int4* iv = reinterpret_cast<const int4*>(idx + t * TOPK);
    const int4 i0 = iv[0], i1 = iv[1], i2 = iv[2], i3 = iv[3];  // L1-hot broadcast

    const float4* wb = reinterpret_cast<const float4*>(w);      // row r: wb[r*256 + tid]

    float ax = 0.f, ay = 0.f, az = 0.f, aw = 0.f;
    {
        const float4 r0 = wb[(size_t)i0.x * (DIM/4) + tid];
        const float4 r1 = wb[(size_t)i0.y * (DIM/4) + tid];
        const float4 r2 = wb[(size_t)i0.z * (DIM/4) + tid];
        const float4 r3 = wb[(size_t)i0.w * (DIM/4) + tid];
        const float4 r4 = wb[(size_t)i1.x * (DIM/4) + tid];
        const float4 r5 = wb[(size_t)i1.y * (DIM/4) + tid];
        const float4 r6 = wb[(size_t)i1.z * (DIM/4) + tid];
        const float4 r7 = wb[(size_t)i1.w * (DIM/4) + tid];
        ax += sg[0]*r0.x; ay += sg[0]*r0.y; az += sg[0]*r0.z; aw += sg[0]*r0.w;
        ax += sg[1]*r1.x; ay += sg[1]*r1.y; az += sg[1]*r1.z; aw += sg[1]*r1.w;
        ax += sg[2]*r2.x; ay += sg[2]*r2.y; az += sg[2]*r2.z; aw += sg[2]*r2.w;
        ax += sg[3]*r3.x; ay += sg[3]*r3.y; az += sg[3]*r3.z; aw += sg[3]*r3.w;
        ax += sg[4]*r4.x; ay += sg[4]*r4.y; az += sg[4]*r4.z; aw += sg[4]*r4.w;
        ax += sg[5]*r5.x; ay += sg[5]*r5.y; az += sg[5]*r5.z; aw += sg[5]*r5.w;
        ax += sg[6]*r6.x; ay += sg[6]*r6.y; az += sg[6]*r6.z; aw += sg[6]*r6.w;
        ax += sg[7]*r7.x; ay += sg[7]*r7.y; az += sg[7]*r7.z; aw += sg[7]*r7.w;
    }
    {
        const float4 r0 = wb[(size_t)i2.x * (DIM/4) + tid];
        const float4 r1 = wb[(size_t)i2.y * (DIM/4) + tid];
        const float4 r2 = wb[(size_t)i2.z * (DIM/4) + tid];
        const float4 r3 = wb[(size_t)i2.w * (DIM/4) + tid];
        const float4 r4 = wb[(size_t)i3.x * (DIM/4) + tid];
        const float4 r5 = wb[(size_t)i3.y * (DIM/4) + tid];
        const float4 r6 = wb[(size_t)i3.z * (DIM/4) + tid];
        const float4 r7 = wb[(size_t)i3.w * (DIM/4) + tid];
        ax += sg[8] *r0.x; ay += sg[8] *r0.y; az += sg[8] *r0.z; aw += sg[8] *r0.w;
        ax += sg[9] *r1.x; ay += sg[9] *r1.y; az += sg[9] *r1.z; aw += sg[9] *r1.w;
        ax += sg[10]*r2.x; ay += sg[10]*r2.y; az += sg[10]*r2.z; aw += sg[10]*r2.w;
        ax += sg[11]*r3.x; ay += sg[11]*r3.y; az += sg[11]*r3.z; aw += sg[11]*r3.w;
        ax += sg[12]*r4.x; ay += sg[12]*r4.y; az += sg[12]*r4.z; aw += sg[12]*r4.w;
        ax += sg[13]*r5.x; ay += sg[13]*r5.y; az += sg[13]*r5.z; aw += sg[13]*r5.w;
        ax += sg[14]*r6.x; ay += sg[14]*r6.y; az += sg[14]*r6.z; aw += sg[14]*r6.w;
        ax += sg[15]*r7.x; ay += sg[15]*r7.y; az += sg[15]*r7.z; aw += sg[15]*r7.w;
    }

    reinterpret_cast<float4*>(out + (size_t)t * DIM)[tid] =
        make_float4(ax, ay, az, aw);
}

extern "C" void kernel_launch(void* const* d_in, const int* in_sizes, int n_in,
                              void* d_out, int out_size, void* d_ws, size_t ws_size,
                              hipStream_t stream) {
    const float* x    = (const float*)d_in[0];  // [B,S,D]
    const float* emb  = (const float*)d_in[1];  // [N,D]
    const float* w    = (const float*)d_in[2];  // [N,D]
    const float* gate = (const float*)d_in[3];  // [B,S,K]
    const int*   idx  = (const int*)d_in[4];    // [B,S,K]
    float*       out  = (float*)d_out;          // [B,S,D]

    kc_fused_kernel<<<TOKENS, NT, 0, stream>>>(x, emb, w, gate, idx, out);
}